// Round 1
// baseline (564.224 us; speedup 1.0000x reference)
//
#include <hip/hip_runtime.h>

namespace {

constexpr int B = 32, T = 128, V = 128, F = 64, O = 64;

// LtT[b][u][v] = L_tilde[b][v][u] = ((v==u) ? deg[b,v]-1 : 0) - W[b,v,u]
// deg[b,j] = sum_i W[b,i,j]   (jnp.sum(W, axis=1))
__global__ __launch_bounds__(256) void prep_ltT(const float* __restrict__ W,
                                                float* __restrict__ LtT) {
    const int b = blockIdx.x;
    const float* Wb = W + (size_t)b * V * V;
    float* Lb = LtT + (size_t)b * V * V;
    __shared__ float deg[V];
    const int tid = threadIdx.x;
    if (tid < V) {
        float s = 0.f;
        for (int i = 0; i < V; ++i) s += Wb[i * V + tid];
        deg[tid] = s;
    }
    __syncthreads();
    for (int idx = tid; idx < V * V; idx += 256) {
        const int u = idx >> 7;
        const int v = idx & (V - 1);
        const float lt = ((u == v) ? (deg[u] - 1.0f) : 0.0f) - Wb[v * V + u];
        Lb[idx] = lt;
    }
}

// One block per (b, t). out[u,o] = Zm[u,o] + sum_v LtT[u,v]*Z1[v,o] + 2*sum_v LtT[u,v]^2*Z2[v,o]
// where Zm = x@(Th0-Th2), Z1 = x@Th1, Z2 = x@Th2 (all per (b,t) row-local in v).
__global__ __launch_bounds__(256, 2) void graph_conv_main(
    const float* __restrict__ x, const float* __restrict__ LtT,
    const float* __restrict__ Theta, float* __restrict__ out) {
    const int t = blockIdx.x;
    const int b = blockIdx.y;
    const int tid = threadIdx.x;

    __shared__ float xs[V][F];      // 32 KiB
    __shared__ float zm[32][O];     // 8 KiB  (chunk of x@(Th0-Th2))
    __shared__ float z1[32][O];     // 8 KiB
    __shared__ float z2[32][O];     // 8 KiB
    __shared__ float lts[V][32];    // 16 KiB (LtT[:, vchunk])
    // total 72 KiB -> 2 blocks/CU

    // ---- stage x[b,t,:,:] into LDS (coalesced float4) ----
    const float* xbt = x + ((size_t)(b * T + t)) * (V * F);
    {
        const float4* src = (const float4*)xbt;
        float4* dst = (float4*)&xs[0][0];
#pragma unroll
        for (int i = 0; i < (V * F / 4) / 256; ++i)  // 8 iters
            dst[tid + i * 256] = src[tid + i * 256];
    }

    const int o = tid & 63;   // output column
    const int g = tid >> 6;   // wave id 0..3: v-group in Z phase, u-group in contraction

    const float* Th0 = Theta;
    const float* Th1 = Theta + F * O;
    const float* Th2 = Theta + 2 * F * O;
    const float* LtTb = LtT + (size_t)b * V * V;

    float acc[32];
#pragma unroll
    for (int j = 0; j < 32; ++j) acc[j] = 0.f;

    for (int c = 0; c < 4; ++c) {
        // barrier: prev chunk's contraction reads (z*, lts) done; also covers xs staging at c=0
        __syncthreads();

        // ---- stage lts[row][0..31] = LtTb[row*V + c*32 + ...] ----
#pragma unroll
        for (int i = 0; i < 4; ++i) {
            const int idx = tid + i * 256;       // 0..1023 float4 slots
            const int row = idx >> 3;
            const int c4 = idx & 7;
            const float4 val = *(const float4*)&LtTb[row * V + c * 32 + c4 * 4];
            *(float4*)&lts[row][c4 * 4] = val;
        }

        // ---- Z phase: rows v = c*32 + g*8 + k, k=0..7 ----
        float am[8], a1[8], a2[8];
#pragma unroll
        for (int k = 0; k < 8; ++k) { am[k] = 0.f; a1[k] = 0.f; a2[k] = 0.f; }
        const int vbase = c * 32 + g * 8;
        for (int f4 = 0; f4 < F; f4 += 4) {
            float t1q[4], t2q[4], tmq[4];
#pragma unroll
            for (int q = 0; q < 4; ++q) {
                const float t0 = Th0[(f4 + q) * O + o];
                t1q[q] = Th1[(f4 + q) * O + o];
                t2q[q] = Th2[(f4 + q) * O + o];
                tmq[q] = t0 - t2q[q];
            }
#pragma unroll
            for (int k = 0; k < 8; ++k) {
                const float4 xv = *(const float4*)&xs[vbase + k][f4];  // broadcast read
                am[k] += xv.x * tmq[0] + xv.y * tmq[1] + xv.z * tmq[2] + xv.w * tmq[3];
                a1[k] += xv.x * t1q[0] + xv.y * t1q[1] + xv.z * t1q[2] + xv.w * t1q[3];
                a2[k] += xv.x * t2q[0] + xv.y * t2q[1] + xv.z * t2q[2] + xv.w * t2q[3];
            }
        }
#pragma unroll
        for (int k = 0; k < 8; ++k) {
            zm[g * 8 + k][o] = am[k];
            z1[g * 8 + k][o] = a1[k];
            z2[g * 8 + k][o] = a2[k];
        }
        __syncthreads();

        // ---- contraction: u = g*32 + j ----
        if (c == g) {
#pragma unroll
            for (int j = 0; j < 32; ++j) acc[j] += zm[j][o];
        }
        for (int vv = 0; vv < 32; vv += 2) {
            const float zz1a = z1[vv][o];
            const float zz2a = 2.0f * z2[vv][o];
            const float zz1b = z1[vv + 1][o];
            const float zz2b = 2.0f * z2[vv + 1][o];
#pragma unroll
            for (int j = 0; j < 32; ++j) {
                const float lta = lts[g * 32 + j][vv];       // b64-pairable broadcast
                const float ltb = lts[g * 32 + j][vv + 1];
                acc[j] += lta * (zz1a + lta * zz2a);         // 2 FMA
                acc[j] += ltb * (zz1b + ltb * zz2b);         // 2 FMA
            }
        }
    }

    // ---- epilogue: relu + store ----
    float* obt = out + ((size_t)(b * T + t)) * (V * O);
#pragma unroll
    for (int j = 0; j < 32; ++j) {
        const float r = acc[j];
        obt[(g * 32 + j) * O + o] = r > 0.f ? r : 0.f;
    }
}

}  // namespace

extern "C" void kernel_launch(void* const* d_in, const int* in_sizes, int n_in,
                              void* d_out, int out_size, void* d_ws, size_t ws_size,
                              hipStream_t stream) {
    const float* x = (const float*)d_in[0];      // (B,T,V,F)
    const float* W = (const float*)d_in[1];      // (B,V,V)
    const float* Theta = (const float*)d_in[2];  // (3,F,O)
    float* outp = (float*)d_out;                 // (B,T,V,O)
    float* ltT = (float*)d_ws;                   // B*V*V floats = 2 MiB

    prep_ltT<<<B, 256, 0, stream>>>(W, ltT);
    graph_conv_main<<<dim3(T, B), 256, 0, stream>>>(x, ltT, Theta, outp);
}

// Round 3
// 81.141 us; speedup vs baseline: 6.9536x; 6.9536x over previous
//
#include <hip/hip_runtime.h>

typedef __attribute__((ext_vector_type(8))) short bf16x8;
typedef __attribute__((ext_vector_type(4))) float f32x4;

namespace {

constexpr int B = 32, T = 128, V = 128, F = 64, O = 64;

// ws layout (bytes): [Acat bf16 B*128*256][ThT bf16 192*64][ldiag f32 B*128]
constexpr size_t WS_THT_OFF = (size_t)B * V * 256 * 2;      // 2 MiB
constexpr size_t WS_LDG_OFF = WS_THT_OFF + 192 * 64 * 2;    // +24 KiB

__device__ inline unsigned short f2bf(float f) {
    unsigned u = __builtin_bit_cast(unsigned, f);
    u += 0x7FFFu + ((u >> 16) & 1u);
    return (unsigned short)(u >> 16);
}

// ---------------- prep: build Acat (zero-diag, bf16), ThT (bf16), ldiag (f32) ----------------
__global__ __launch_bounds__(256) void prep(const float* __restrict__ W,
                                            const float* __restrict__ Theta,
                                            unsigned short* __restrict__ acat,
                                            unsigned short* __restrict__ tht,
                                            float* __restrict__ ldg) {
    const int tid = threadIdx.x;
    if (blockIdx.x == B) {
        // ThT[n][f]: n in [0,192) = [Th0-Th2 | Th1 | Th2] columns, f in [0,64)
        for (int i = 0; i < 192 * 64 / 256; ++i) {
            int idx = tid + i * 256;
            int n = idx >> 6, f = idx & 63;
            float v;
            if (n < 64)       v = Theta[f * 64 + n] - Theta[2 * 4096 + f * 64 + n];
            else if (n < 128) v = Theta[4096 + f * 64 + (n - 64)];
            else              v = Theta[2 * 4096 + f * 64 + (n - 128)];
            tht[idx] = f2bf(v);
        }
        return;
    }
    const int b = blockIdx.x;
    const float* Wb = W + (size_t)b * V * V;
    __shared__ float Wl[V][V + 1];
    for (int i = 0; i < V * V / 256; ++i) {
        int idx = tid + i * 256;
        Wl[idx >> 7][idx & 127] = Wb[idx];
    }
    __syncthreads();
    if (tid < V) {
        float s = 0.f;
        for (int i = 0; i < V; ++i) s += Wl[i][tid];       // deg[u] = sum_i W[i][u]
        ldg[b * V + tid] = s - 1.0f - Wl[tid][tid];        // ldiag
    }
    unsigned short* ab = acat + (size_t)b * V * 256;
    for (int i = 0; i < V; ++i) {                          // 32768/256 iters
        int idx = tid + i * 256;
        int u = idx >> 8, kv = idx & 255, v = kv & 127;
        float wv = Wl[v][u];
        float val = (v == u) ? 0.f : ((kv < 128) ? -wv : 2.f * wv * wv);
        ab[idx] = f2bf(val);
    }
}

// ---------------- main: per (b,t): Z = xs@ThT (MFMA), out = Zm + diag-term + Acat@Zcat ----------------
__global__ __launch_bounds__(256, 3) void graph_conv_main(
    const float* __restrict__ x, const unsigned short* __restrict__ acat,
    const unsigned short* __restrict__ tht_g, const float* __restrict__ ldg,
    float* __restrict__ out) {
    const int t = blockIdx.x, b = blockIdx.y;
    const int tid = threadIdx.x;
    const int lane = tid & 63, w = tid >> 6;
    const int lr = lane & 15, lg = lane >> 4;

    // smem: phase1 = [xs: 128x64 bf16 (16KB) | tht: 192x64 bf16 (24KB)]
    //       phase2 = zct: 64 rows x 256 cols bf16 (32KB), aliases phase1
    __shared__ __align__(16) unsigned short smem[20480];
    __shared__ __align__(16) float ldg_s[V];
    unsigned short* xs = smem;
    unsigned short* th = smem + 8192;
    unsigned short* zct = smem;

    // ---- stage xs (fp32 -> bf16, XOR-swizzled rows of 128B) ----
    const float* xbt = x + ((size_t)(b * T + t)) * (V * F);
#pragma unroll
    for (int i = 0; i < 4; ++i) {              // 1024 chunks of 8 elems = 8192 = V*F  (was the r2 bug: i<2 staged only rows 0..63)
        int c = tid + i * 256;
        int row = c >> 3, c8 = c & 7;
        const float4* p = (const float4*)(xbt + row * 64 + c8 * 8);
        float4 q0 = p[0], q1 = p[1];
        uint4 val;
        val.x = f2bf(q0.x) | ((unsigned)f2bf(q0.y) << 16);
        val.y = f2bf(q0.z) | ((unsigned)f2bf(q0.w) << 16);
        val.z = f2bf(q1.x) | ((unsigned)f2bf(q1.y) << 16);
        val.w = f2bf(q1.z) | ((unsigned)f2bf(q1.w) << 16);
        int off = row * 128 + ((c8 * 16) ^ ((row & 7) << 4));
        *(uint4*)((char*)xs + off) = val;
    }
    // ---- stage ThT (bf16 copy, swizzled) ----
#pragma unroll
    for (int i = 0; i < 6; ++i) {
        int c = tid + i * 256;                 // 1536 chunks
        int row = c >> 3, c8 = c & 7;
        uint4 val = *(const uint4*)(tht_g + row * 64 + c8 * 8);
        int off = row * 128 + ((c8 * 16) ^ ((row & 7) << 4));
        *(uint4*)((char*)th + off) = val;
    }
    if (tid < V) ldg_s[tid] = ldg[b * V + tid];
    __syncthreads();

    // ---- Z phase: rows v in [32w, 32w+32). acc gets Zm directly; z[][0..3]=Z1, z[][4..7]=Z2 ----
    f32x4 acc[2][4];
    f32x4 z[2][8];
#pragma unroll
    for (int vf = 0; vf < 2; ++vf) {
#pragma unroll
        for (int of = 0; of < 4; ++of) acc[vf][of] = (f32x4){0.f, 0.f, 0.f, 0.f};
#pragma unroll
        for (int nf = 0; nf < 8; ++nf) z[vf][nf] = (f32x4){0.f, 0.f, 0.f, 0.f};
    }
#pragma unroll
    for (int ks = 0; ks < 2; ++ks) {
        bf16x8 xa[2];
#pragma unroll
        for (int vf = 0; vf < 2; ++vf) {
            int row = w * 32 + 16 * vf + lr;
            int off = row * 128 + ((ks * 64 + lg * 16) ^ ((row & 7) << 4));
            xa[vf] = *(const bf16x8*)((const char*)xs + off);
        }
#pragma unroll
        for (int nf = 0; nf < 12; ++nf) {
            int rowt = nf * 16 + lr;
            int off = rowt * 128 + ((ks * 64 + lg * 16) ^ ((rowt & 7) << 4));
            bf16x8 tb = *(const bf16x8*)((const char*)th + off);
            if (nf < 4) {
                acc[0][nf] = __builtin_amdgcn_mfma_f32_16x16x32_bf16(xa[0], tb, acc[0][nf], 0, 0, 0);
                acc[1][nf] = __builtin_amdgcn_mfma_f32_16x16x32_bf16(xa[1], tb, acc[1][nf], 0, 0, 0);
            } else {
                z[0][nf - 4] = __builtin_amdgcn_mfma_f32_16x16x32_bf16(xa[0], tb, z[0][nf - 4], 0, 0, 0);
                z[1][nf - 4] = __builtin_amdgcn_mfma_f32_16x16x32_bf16(xa[1], tb, z[1][nf - 4], 0, 0, 0);
            }
        }
    }

    // ---- fp32 diagonal term: acc += ldiag*Z1 + 2*ldiag^2*Z2 (row mapping identical: v-slab == u-slab) ----
#pragma unroll
    for (int vf = 0; vf < 2; ++vf) {
        f32x4 ld = *(const f32x4*)(ldg_s + w * 32 + 16 * vf + lg * 4);
        f32x4 ld2 = 2.0f * ld * ld;
#pragma unroll
        for (int of = 0; of < 4; ++of)
            acc[vf][of] += ld * z[vf][of] + ld2 * z[vf][4 + of];
    }

    __syncthreads();   // all xs/th reads complete before zct overwrite

    // ---- write ZcatT[o][kv] bf16 (o-major, swizzled): kv<128 = Z1, kv>=128 = Z2 ----
#pragma unroll
    for (int vf = 0; vf < 2; ++vf) {
        int vcol = w * 32 + 16 * vf + lg * 4;
#pragma unroll
        for (int of = 0; of < 4; ++of) {
            int rowz = of * 16 + lr;
            f32x4 z1 = z[vf][of], z2 = z[vf][4 + of];
            uint2 q1, q2;
            q1.x = f2bf(z1[0]) | ((unsigned)f2bf(z1[1]) << 16);
            q1.y = f2bf(z1[2]) | ((unsigned)f2bf(z1[3]) << 16);
            q2.x = f2bf(z2[0]) | ((unsigned)f2bf(z2[1]) << 16);
            q2.y = f2bf(z2[2]) | ((unsigned)f2bf(z2[3]) << 16);
            int base = rowz * 512;
            *(uint2*)((char*)zct + base + (((vcol * 2)) ^ ((rowz & 7) << 4))) = q1;
            *(uint2*)((char*)zct + base + ((256 + vcol * 2) ^ ((rowz & 7) << 4))) = q2;
        }
    }
    __syncthreads();

    // ---- contraction: acc += Acat[u, 0:256] @ Zcat ----
    const unsigned short* ab = acat + (size_t)b * V * 256;
#pragma unroll
    for (int ks = 0; ks < 8; ++ks) {
        bf16x8 af[2];
#pragma unroll
        for (int uf = 0; uf < 2; ++uf) {
            int rowa = w * 32 + 16 * uf + lr;
            af[uf] = *(const bf16x8*)(ab + rowa * 256 + ks * 32 + lg * 8);
        }
#pragma unroll
        for (int of = 0; of < 4; ++of) {
            int rowz = of * 16 + lr;
            int off = rowz * 512 + ((ks * 64 + lg * 16) ^ ((rowz & 7) << 4));
            bf16x8 zb = *(const bf16x8*)((const char*)zct + off);
            acc[0][of] = __builtin_amdgcn_mfma_f32_16x16x32_bf16(af[0], zb, acc[0][of], 0, 0, 0);
            acc[1][of] = __builtin_amdgcn_mfma_f32_16x16x32_bf16(af[1], zb, acc[1][of], 0, 0, 0);
        }
    }

    // ---- epilogue: relu + store ----
    float* obt = out + ((size_t)(b * T + t)) * (V * O);
#pragma unroll
    for (int vf = 0; vf < 2; ++vf)
#pragma unroll
        for (int of = 0; of < 4; ++of)
#pragma unroll
            for (int j = 0; j < 4; ++j) {
                int u = w * 32 + 16 * vf + lg * 4 + j;
                int o = of * 16 + lr;
                float r = acc[vf][of][j];
                obt[u * 64 + o] = r > 0.f ? r : 0.f;
            }
}

}  // namespace

extern "C" void kernel_launch(void* const* d_in, const int* in_sizes, int n_in,
                              void* d_out, int out_size, void* d_ws, size_t ws_size,
                              hipStream_t stream) {
    const float* x = (const float*)d_in[0];      // (B,T,V,F)
    const float* W = (const float*)d_in[1];      // (B,V,V)
    const float* Theta = (const float*)d_in[2];  // (3,F,O)
    float* outp = (float*)d_out;                 // (B,T,V,O)

    unsigned short* acat = (unsigned short*)d_ws;
    unsigned short* tht = (unsigned short*)((char*)d_ws + WS_THT_OFF);
    float* ldg = (float*)((char*)d_ws + WS_LDG_OFF);

    prep<<<B + 1, 256, 0, stream>>>(W, Theta, acat, tht, ldg);
    graph_conv_main<<<dim3(T, B), 256, 0, stream>>>(x, acat, tht, ldg, outp);
}